// Round 7
// baseline (151.030 us; speedup 1.0000x reference)
//
#include <hip/hip_runtime.h>
#include <hip/hip_bf16.h>
#include <math.h>

#define N_PTS 32768
#define IN_F  256
#define NUM_CAT 16
#define CF    4096
#define NSEG  6
#define OUTK  50
#define BN_EPS 1e-5f

typedef unsigned short u16;
typedef __attribute__((ext_vector_type(8))) short bf16x8;
typedef __attribute__((ext_vector_type(4))) float f32x4;
typedef __attribute__((ext_vector_type(8))) unsigned short u16x8;

// ---- ws layout (float offsets) ----
#define OFF_G     0u          // 256*256
#define OFF_FBAR  65536u      // 256
#define OFF_SCALE 65792u      // 4096
#define OFF_SHIFT 69888u      // 4096
#define OFF_INT   73984u      // int region (33440 ints)
#define OFF_FB    107424u     // F bf16 [32768][256]
#define OFF_FBT   4301728u    // F^T bf16 [256][32768]
#define OFF_W1T   8496032u    // W1T bf16 [16][256 n][256 k]
#define OFF_GP    9020320u    // Gram partials [chunk][40960]
#define IO_COUNTS 0
#define IO_CATOFF 16
#define IO_TILEST 33
#define IO_NTILES 50
#define IO_CURSOR 51
#define IO_ORDER  67
#define IO_TILECAT 32835      // 528 packed ints: c | (npts-1)<<4 | base<<10

__device__ __forceinline__ void gload_lds16(const void* g, void* l) {
    __builtin_amdgcn_global_load_lds(
        (const __attribute__((address_space(1))) void*)g,
        (__attribute__((address_space(3))) void*)l,
        16, 0, 0);
}
__device__ __forceinline__ u16 f2bf(float f) {
    unsigned int u = __float_as_uint(f);
    return (u16)((u + 0x7FFF + ((u >> 16) & 1)) >> 16);
}
__device__ __forceinline__ float bf2f(u16 h) {
    return __uint_as_float((unsigned int)h << 16);
}

// ============ K0: F -> Fb (row-major bf16) AND FbT (transposed bf16) ============
__global__ __launch_bounds__(256) void k0_cvt(const float* __restrict__ F,
                                              u16* __restrict__ Fb,
                                              u16* __restrict__ FbT) {
    const int pb = blockIdx.x >> 2, fb = blockIdx.x & 3;
    const int p0 = pb * 64, f0 = fb * 64;
    const int tid = threadIdx.x;
    __shared__ u16 T[64][72];
    {
        int p = tid >> 2, fq = tid & 3;
        const float* src = &F[(size_t)(p0 + p) * IN_F + f0 + fq * 16];
        u16x8 o0, o1;
        float4 v0 = *(const float4*)&src[0];
        float4 v1 = *(const float4*)&src[4];
        float4 v2 = *(const float4*)&src[8];
        float4 v3 = *(const float4*)&src[12];
        o0[0]=f2bf(v0.x); o0[1]=f2bf(v0.y); o0[2]=f2bf(v0.z); o0[3]=f2bf(v0.w);
        o0[4]=f2bf(v1.x); o0[5]=f2bf(v1.y); o0[6]=f2bf(v1.z); o0[7]=f2bf(v1.w);
        o1[0]=f2bf(v2.x); o1[1]=f2bf(v2.y); o1[2]=f2bf(v2.z); o1[3]=f2bf(v2.w);
        o1[4]=f2bf(v3.x); o1[5]=f2bf(v3.y); o1[6]=f2bf(v3.z); o1[7]=f2bf(v3.w);
        u16* dst = &Fb[(size_t)(p0 + p) * IN_F + f0 + fq * 16];
        *(u16x8*)dst = o0; *(u16x8*)&dst[8] = o1;
        *(u16x8*)&T[p][fq * 16] = o0; *(u16x8*)&T[p][fq * 16 + 8] = o1;
    }
    __syncthreads();
    {
        int f = tid >> 2, pq = tid & 3;
        u16x8 a0, a1;
#pragma unroll
        for (int m = 0; m < 8; m++) { a0[m] = T[pq*16 + m][f]; a1[m] = T[pq*16 + 8 + m][f]; }
        u16* dst = &FbT[(size_t)(f0 + f) * N_PTS + p0 + pq * 16];
        *(u16x8*)dst = a0; *(u16x8*)&dst[8] = a1;
    }
}

// ============ K0b: W1 [256][4096] -> W1T bf16 [c][n][k] ============
__global__ __launch_bounds__(256) void k0b_w1t(const float* __restrict__ W1,
                                               u16* __restrict__ W1T) {
    __shared__ u16 T[64][65];
    const int kb = blockIdx.x & 3, jb = blockIdx.x >> 2;
    const int tid = threadIdx.x;
    {
        int kk = tid >> 2, j4 = (tid & 3) * 16;
        const float* src = &W1[(size_t)(kb * 64 + kk) * CF + jb * 64 + j4];
#pragma unroll
        for (int q = 0; q < 4; q++) {
            float4 v = *(const float4*)&src[q * 4];
            T[kk][j4 + q * 4 + 0] = f2bf(v.x); T[kk][j4 + q * 4 + 1] = f2bf(v.y);
            T[kk][j4 + q * 4 + 2] = f2bf(v.z); T[kk][j4 + q * 4 + 3] = f2bf(v.w);
        }
    }
    __syncthreads();
    {
        int jj = tid >> 2, ks = (tid & 3) * 16;
        int c = jb >> 2, n = (jb & 3) * 64 + jj;
        u16* dst = &W1T[((size_t)(c * 256 + n)) * 256 + kb * 64 + ks];
        u16x8 o0, o1;
#pragma unroll
        for (int m = 0; m < 8; m++) { o0[m] = T[ks + m][jj]; o1[m] = T[ks + 8 + m][jj]; }
        *(u16x8*)dst = o0;
        *(u16x8*)&dst[8] = o1;
    }
}

// ============ K1: Gram via bf16 MFMA (10 symmetric tiles x nchunk K-chunks) ============
__global__ __launch_bounds__(256) void k1_gram(const u16* __restrict__ FbT,
                                               float* __restrict__ ws,
                                               int nchunk, int Kc) {
    const int TI[10] = {0,0,0,0,1,1,1,2,2,3};
    const int TJ[10] = {0,1,2,3,1,2,3,2,3,3};
    const int t = blockIdx.x % 10, chunk = blockIdx.x / 10;
    const int i0 = TI[t] * 64, j0 = TJ[t] * 64;
    const int r0 = chunk * Kc;
    const int tid = threadIdx.x;
    const int wv = tid >> 6, ln = tid & 63, g = ln >> 4, r16 = ln & 15;
    __shared__ __align__(16) u16 SA[2][4096];
    __shared__ __align__(16) u16 SB[2][4096];

    const int q0 = wv * 2, q1 = wv * 2 + 1;
    const int u_a = ((q0 * 64 + ln) & 7), row_a = (q0 * 64 + ln) >> 3;
    const int u_b = ((q1 * 64 + ln) & 7), row_b = (q1 * 64 + ln) >> 3;
    const int ka = ((u_a ^ (row_a & 7)) << 3), kb2 = ((u_b ^ (row_b & 7)) << 3);

    f32x4 acc[4];
#pragma unroll
    for (int nt = 0; nt < 4; nt++)
#pragma unroll
        for (int i = 0; i < 4; i++) acc[nt][i] = 0.f;

    const int nslab = Kc >> 6;
#define K1_STAGE(s, b)                                                              \
    {   int p0s = r0 + (s) * 64;                                                    \
        gload_lds16(FbT + (size_t)(i0 + row_a) * N_PTS + p0s + ka,                  \
                    (char*)SA[b] + q0 * 1024);                                      \
        gload_lds16(FbT + (size_t)(i0 + row_b) * N_PTS + p0s + kb2,                 \
                    (char*)SA[b] + q1 * 1024);                                      \
        gload_lds16(FbT + (size_t)(j0 + row_a) * N_PTS + p0s + ka,                  \
                    (char*)SB[b] + q0 * 1024);                                      \
        gload_lds16(FbT + (size_t)(j0 + row_b) * N_PTS + p0s + kb2,                 \
                    (char*)SB[b] + q1 * 1024);                                      \
    }

    K1_STAGE(0, 0);
    __syncthreads();
    for (int s = 0; s < nslab; s++) {
        const int b = s & 1;
        if (s + 1 < nslab) K1_STAGE(s + 1, b ^ 1);
#pragma unroll
        for (int ks = 0; ks < 2; ks++) {
            int ph = (ks * 4 + g) ^ (r16 & 7);
            bf16x8 a = *(const bf16x8*)((const char*)SA[b] + (wv * 16 + r16) * 128 + ph * 16);
#pragma unroll
            for (int nt = 0; nt < 4; nt++) {
                int nB = nt * 16 + r16;
                bf16x8 bb = *(const bf16x8*)((const char*)SB[b] + nB * 128 + ph * 16);
                acc[nt] = __builtin_amdgcn_mfma_f32_16x16x32_bf16(a, bb, acc[nt], 0, 0, 0);
            }
        }
        __syncthreads();
    }
    float* Gp = ws + OFF_GP + (size_t)chunk * 40960 + t * 4096;
#pragma unroll
    for (int nt = 0; nt < 4; nt++)
#pragma unroll
        for (int i = 0; i < 4; i++) {
            int row = wv * 16 + g * 4 + i, col = nt * 16 + r16;
            Gp[row * 64 + col] = acc[nt][i];
        }
}

// ============ K1b: column means from FbT; zero category counts ============
__global__ __launch_bounds__(256) void k1b_colsum(const u16* __restrict__ FbT,
                                                  float* __restrict__ ws) {
    const int row = blockIdx.x, tid = threadIdx.x;
    const u16* r = FbT + (size_t)row * N_PTS;
    float s = 0.f;
    for (int i = tid * 8; i < N_PTS; i += 2048) {
        u16x8 v = *(const u16x8*)&r[i];
#pragma unroll
        for (int m = 0; m < 8; m++) s += bf2f(v[m]);
    }
#pragma unroll
    for (int off = 32; off >= 1; off >>= 1) s += __shfl_xor(s, off);
    __shared__ float ps[4];
    if ((tid & 63) == 0) ps[tid >> 6] = s;
    __syncthreads();
    if (tid == 0) ws[OFF_FBAR + row] = (ps[0] + ps[1] + ps[2] + ps[3]) * (1.0f / N_PTS);
    if (blockIdx.x == 0 && tid < 16) ((int*)(ws + OFF_INT))[IO_COUNTS + tid] = 0;
}

// ============ K2a: coalesced reduce of Gram partials -> symmetric G ============
__global__ __launch_bounds__(256) void k2a_reduce(float* __restrict__ ws, int nchunk) {
    const int TI[10] = {0,0,0,0,1,1,1,2,2,3};
    const int TJ[10] = {0,1,2,3,1,2,3,2,3,3};
    const int e = blockIdx.x * 256 + threadIdx.x;   // 0..40959
    const float* p = ws + OFF_GP + e;
    float s = 0.f;
#pragma unroll 8
    for (int c = 0; c < nchunk; c++) s += p[(size_t)c * 40960];
    int t = e >> 12, x = (e >> 6) & 63, y = e & 63;
    int a = TI[t] * 64 + x, b = TJ[t] * 64 + y;
    ws[OFF_G + a * 256 + b] = s;
    ws[OFF_G + b * 256 + a] = s;
}

// ============ K2b: per-column mu/var -> scale/shift ============
__global__ __launch_bounds__(256) void k2b_stats(const float* __restrict__ W1,
                                                 const float* __restrict__ gamma,
                                                 const float* __restrict__ beta,
                                                 float* __restrict__ ws) {
    const int tid = threadIdx.x;
    const int j0 = blockIdx.x * 16;
    __shared__ __align__(16) float wl[16][256];
    __shared__ float pw[16][8];
#pragma unroll
    for (int q = 0; q < 4; q++) {
        float4 v = *(const float4*)&W1[(size_t)tid * CF + j0 + q * 4];
        wl[q * 4 + 0][tid] = v.x; wl[q * 4 + 1][tid] = v.y;
        wl[q * 4 + 2][tid] = v.z; wl[q * 4 + 3][tid] = v.w;
    }
    __syncthreads();
    float acc[16];
#pragma unroll
    for (int jj = 0; jj < 16; jj++) acc[jj] = 0.f;
    const float* G = ws + OFF_G;
    for (int b = 0; b < 256; b++) {
        float g = G[b * 256 + tid];
#pragma unroll
        for (int jj = 0; jj < 16; jj++) acc[jj] += g * wl[jj][b];
    }
    float fb = ws[OFF_FBAR + tid];
    const int lane = tid & 63, wave = tid >> 6;
#pragma unroll
    for (int jj = 0; jj < 16; jj++) {
        float v = wl[jj][tid] * acc[jj];
        float m = fb * wl[jj][tid];
#pragma unroll
        for (int off = 32; off >= 1; off >>= 1) {
            v += __shfl_xor(v, off);
            m += __shfl_xor(m, off);
        }
        if (lane == 0) { pw[jj][wave * 2] = v; pw[jj][wave * 2 + 1] = m; }
    }
    __syncthreads();
    if (tid < 16) {
        int jj = tid;
        float v = 0.f, m = 0.f;
        for (int w2 = 0; w2 < 4; w2++) { v += pw[jj][w2 * 2]; m += pw[jj][w2 * 2 + 1]; }
        float mu  = m;
        float var = v * (1.0f / N_PTS) - mu * mu;
        float sc  = gamma[j0 + jj] * rsqrtf(var + BN_EPS);
        float sh  = beta[j0 + jj] - mu * sc;
        ws[OFF_SCALE + j0 + jj] = sc;
        ws[OFF_SHIFT + j0 + jj] = sh;
    }
}

// ============ K3: category histogram ============
__global__ __launch_bounds__(256) void k3_hist(const int* __restrict__ cats,
                                               float* __restrict__ ws) {
    __shared__ int h[16];
    int tid = threadIdx.x;
    if (tid < 16) h[tid] = 0;
    __syncthreads();
    for (int n = blockIdx.x * 256 + tid; n < N_PTS; n += 64 * 256)
        atomicAdd(&h[cats[n]], 1);
    __syncthreads();
    int* wi = (int*)(ws + OFF_INT);
    if (tid < 16) atomicAdd(&wi[IO_COUNTS + tid], h[tid]);
}

// ============ K4: prefix sums + packed per-tile LUT ============
__global__ void k4_prefix(float* __restrict__ ws) {
    int* wi = (int*)(ws + OFF_INT);
    if (threadIdx.x == 0) {
        int co = 0, ts = 0;
        wi[IO_CATOFF] = 0; wi[IO_TILEST] = 0;
        for (int c = 0; c < 16; c++) {
            int cnt = wi[IO_COUNTS + c];
            wi[IO_CURSOR + c] = co;
            int nt = (cnt + 63) >> 6;
            for (int lt = 0; lt < nt; lt++) {
                int npts = min(64, cnt - lt * 64);
                int b = co + lt * 64;
                wi[IO_TILECAT + ts + lt] = c | ((npts - 1) << 4) | (b << 10);
            }
            co += cnt; ts += nt;
            wi[IO_CATOFF + c + 1] = co;
            wi[IO_TILEST + c + 1] = ts;
        }
        wi[IO_NTILES] = ts;
    }
}

// ============ K4b: grouped scatter, two-level (block reservation + LDS ranks) ====
__global__ __launch_bounds__(256) void k4b_scatter(const int* __restrict__ cats,
                                                   float* __restrict__ ws) {
    int* wi = (int*)(ws + OFF_INT);
    __shared__ int lh[16], lbase[16];
    const int tid = threadIdx.x;
    const int n0 = blockIdx.x * 512;
    if (tid < 16) lh[tid] = 0;
    __syncthreads();
    const int cA = cats[n0 + tid];
    const int cB = cats[n0 + 256 + tid];
    atomicAdd(&lh[cA], 1);
    atomicAdd(&lh[cB], 1);
    __syncthreads();
    if (tid < 16) lbase[tid] = atomicAdd(&wi[IO_CURSOR + tid], lh[tid]);
    __syncthreads();
    if (tid < 16) lh[tid] = 0;
    __syncthreads();
    int rA = atomicAdd(&lh[cA], 1);
    wi[IO_ORDER + lbase[cA] + rA] = n0 + tid;
    int rB = atomicAdd(&lh[cB], 1);
    wi[IO_ORDER + lbase[cB] + rB] = n0 + 256 + tid;
}

// ============ K5: bf16-MFMA GEMM, all operands in LDS, barrier-free K-loop ====
// 512 threads (8 waves). Wave wv owns cols wv*32..wv*32+31.
// LDS U: F [64pt][512B] at 0 (unit XOR (pt&7)); W ping-pong 2x32KB at 32768:
//   per buffer [wave][32 rows][128 B] (quarter of K), unit XOR (n&7).
// Per-wave W staging (4 gload_lds per quarter) -> no cross-wave W dependency ->
// K-loop uses per-wave s_waitcnt vmcnt(N), zero barriers.
__global__ __launch_bounds__(512) void k5_mfma(const u16* __restrict__ Fb,
                                               const u16* __restrict__ W1T,
                                               const float* __restrict__ Wc,
                                               const float* __restrict__ bias,
                                               const int* __restrict__ shifts,
                                               const int* __restrict__ seg_lens,
                                               const float* __restrict__ ws,
                                               float* __restrict__ out) {
    const int* wi = (const int*)(ws + OFF_INT);
    const int t = blockIdx.x;
    if (t >= wi[IO_NTILES]) return;
    const unsigned info = (unsigned)wi[IO_TILECAT + t];
    const int c    = info & 15;
    const int npts = ((info >> 4) & 63) + 1;
    const int base = info >> 10;
    const int tid = threadIdx.x;
    const int wv = tid >> 6, ln = tid & 63;
    const int g = ln >> 4, r16 = ln & 15;

    __shared__ __align__(16) unsigned char U[98304];   // F 32K | W 2x32K
    __shared__ float scl[256], shl[256], wcl[1536];
    __shared__ int plds[64];

    if (tid < 64) plds[tid] = wi[IO_ORDER + base + min(tid, npts - 1)];
    if (tid < 256) {
        scl[tid] = ws[OFF_SCALE + c * 256 + tid];
        shl[tid] = ws[OFF_SHIFT + c * 256 + tid];
    }
#pragma unroll
    for (int i = 0; i < 3; i++) wcl[tid + i * 512] = Wc[(size_t)c * 1536 + tid + i * 512];
    __syncthreads();

    const u16* W1Tc = W1T + (size_t)c * 65536;

    // per-wave W quarter staging: rows wv*32..+31, 8 x 16B units per row
#define STAGE_WQ(q, b)                                                             \
    {                                                                              \
        _Pragma("unroll")                                                          \
        for (int i2 = 0; i2 < 4; i2++) {                                           \
            int f = i2 * 64 + ln;                                                  \
            int r = f >> 3, u = f & 7;                                             \
            int n = wv * 32 + r;                                                   \
            const u16* src = W1Tc + (size_t)n * 256 + (q) * 64 + ((u ^ (n & 7)) << 3); \
            gload_lds16(src, U + 32768 + (b) * 32768 + wv * 4096 + i2 * 1024);     \
        }                                                                          \
    }

    STAGE_WQ(0, 0);
    STAGE_WQ(1, 1);
    // F tile: 2048 16B units, 4 gload_lds per wave
#pragma unroll
    for (int s = 0; s < 4; s++) {
        int flat = (wv * 4 + s) * 64 + ln;
        int pt = flat >> 5, u = flat & 31;
        const u16* src = Fb + (size_t)plds[pt] * 256 + ((u ^ (pt & 7)) << 3);
        gload_lds16(src, U + (size_t)(wv * 4 + s) * 1024);
    }
    __syncthreads();   // one-time: F + W q0/q1 resident, vmcnt drained

    f32x4 acc[4][2];
#pragma unroll
    for (int mt = 0; mt < 4; mt++)
#pragma unroll
        for (int nt = 0; nt < 2; nt++)
#pragma unroll
            for (int i = 0; i < 4; i++) acc[mt][nt][i] = 0.f;

    // compute one K-quarter (2 kc) from buffer b
#define COMP_Q(q, b)                                                               \
    {                                                                              \
        _Pragma("unroll")                                                          \
        for (int h = 0; h < 2; h++) {                                              \
            const int kc = (q) * 2 + h;                                            \
            bf16x8 af[4], bfr[2];                                                  \
            _Pragma("unroll")                                                      \
            for (int mt = 0; mt < 4; mt++) {                                       \
                int row = mt * 16 + r16;                                           \
                int phys = (kc * 4 + g) ^ (row & 7);                               \
                af[mt] = *(const bf16x8*)(U + (size_t)row * 512 + phys * 16);      \
            }                                                                      \
            _Pragma("unroll")                                                      \
            for (int nt = 0; nt < 2; nt++) {                                       \
                int n = wv * 32 + nt * 16 + r16;                                   \
                int r = nt * 16 + r16;                                             \
                int phys = (h * 4 + g) ^ (n & 7);                                  \
                bfr[nt] = *(const bf16x8*)(U + 32768 + (b) * 32768                 \
                                           + wv * 4096 + r * 128 + phys * 16);    \
            }                                                                      \
            _Pragma("unroll")                                                      \
            for (int mt = 0; mt < 4; mt++)                                         \
                _Pragma("unroll")                                                  \
                for (int nt = 0; nt < 2; nt++)                                     \
                    acc[mt][nt] = __builtin_amdgcn_mfma_f32_16x16x32_bf16(         \
                        af[mt], bfr[nt], acc[mt][nt], 0, 0, 0);                    \
        }                                                                          \
    }

    COMP_Q(0, 0);
    __builtin_amdgcn_sched_barrier(0);       // q0 reads done before overwrite issue
    STAGE_WQ(2, 0);                          // 4 outstanding
    COMP_Q(1, 1);
    __builtin_amdgcn_sched_barrier(0);
    STAGE_WQ(3, 1);                          // 8 outstanding
    asm volatile("s_waitcnt vmcnt(4)" ::: "memory");   // q2 landed
    __builtin_amdgcn_sched_barrier(0);
    COMP_Q(2, 0);
    asm volatile("s_waitcnt vmcnt(0)" ::: "memory");   // q3 landed
    __builtin_amdgcn_sched_barrier(0);
    COMP_Q(3, 1);

    __syncthreads();   // all waves done with F region
    float* red2 = (float*)U;                 // [64 pt][8 wv][6]
#pragma unroll
    for (int mt = 0; mt < 4; mt++)
#pragma unroll
        for (int i = 0; i < 4; i++) {
            float pl[6] = {0.f, 0.f, 0.f, 0.f, 0.f, 0.f};
#pragma unroll
            for (int nt = 0; nt < 2; nt++) {
                int col = wv * 32 + nt * 16 + r16;
                float x = acc[mt][nt][i] * scl[col] + shl[col];
                x = (x >= 0.f) ? x : 0.2f * x;
#pragma unroll
                for (int s = 0; s < 6; s++) pl[s] += x * wcl[col * 6 + s];
            }
#pragma unroll
            for (int s = 0; s < 6; s++) {
                pl[s] += __shfl_xor(pl[s], 1);
                pl[s] += __shfl_xor(pl[s], 2);
                pl[s] += __shfl_xor(pl[s], 4);
                pl[s] += __shfl_xor(pl[s], 8);
            }
            if (r16 == 0) {
                int pt = mt * 16 + g * 4 + i;
#pragma unroll
                for (int s = 0; s < 6; s++) red2[(pt * 8 + wv) * 6 + s] = pl[s];
            }
        }
    __syncthreads();

    if (tid < 64 && tid < npts) {
        float lg[6];
#pragma unroll
        for (int s = 0; s < 6; s++) lg[s] = bias[s];
#pragma unroll
        for (int w = 0; w < 8; w++)
#pragma unroll
            for (int s = 0; s < 6; s++) lg[s] += red2[(tid * 8 + w) * 6 + s];
        float mx = lg[0];
#pragma unroll
        for (int s = 1; s < 6; s++) mx = fmaxf(mx, lg[s]);
        float se = 0.f;
#pragma unroll
        for (int s = 0; s < 6; s++) se += expf(lg[s] - mx);
        float lse = mx + logf(se);
        const int pid = plds[tid];
        const int sh = shifts[c], ln2 = seg_lens[c];
        float* orow = out + (size_t)pid * OUTK;
        for (int k = 0; k < OUTK; k++) {
            int j = k - sh;
            orow[k] = (j >= 0 && j < ln2) ? (lg[j] - lse) : 0.f;
        }
    }
}

extern "C" void kernel_launch(void* const* d_in, const int* in_sizes, int n_in,
                              void* d_out, int out_size, void* d_ws, size_t ws_size,
                              hipStream_t stream) {
    const float* F      = (const float*)d_in[0];
    const float* W1     = (const float*)d_in[1];
    const float* gamma  = (const float*)d_in[2];
    const float* beta   = (const float*)d_in[3];
    const float* Wc     = (const float*)d_in[4];
    const float* bias   = (const float*)d_in[5];
    const int*  cats    = (const int*)d_in[6];
    const int*  shifts  = (const int*)d_in[7];
    const int*  seglens = (const int*)d_in[8];
    float* out = (float*)d_out;
    float* ws  = (float*)d_ws;
    u16* Fb  = (u16*)(ws + OFF_FB);
    u16* FbT = (u16*)(ws + OFF_FBT);
    u16* W1T = (u16*)(ws + OFF_W1T);

    int nchunk = 64;
    if (ws_size < ((size_t)OFF_GP + 40960ull * 64) * 4) nchunk = 32;
    if (ws_size < ((size_t)OFF_GP + 40960ull * 32) * 4) nchunk = 16;
    const int Kc = N_PTS / nchunk;

    hipLaunchKernelGGL(k0_cvt,      dim3(2048), dim3(256), 0, stream, F, Fb, FbT);
    hipLaunchKernelGGL(k0b_w1t,     dim3(256),  dim3(256), 0, stream, W1, W1T);
    hipLaunchKernelGGL(k1_gram,     dim3(10 * nchunk), dim3(256), 0, stream, FbT, ws, nchunk, Kc);
    hipLaunchKernelGGL(k1b_colsum,  dim3(256),  dim3(256), 0, stream, FbT, ws);
    hipLaunchKernelGGL(k2a_reduce,  dim3(160),  dim3(256), 0, stream, ws, nchunk);
    hipLaunchKernelGGL(k2b_stats,   dim3(256),  dim3(256), 0, stream, W1, gamma, beta, ws);
    hipLaunchKernelGGL(k3_hist,     dim3(64),   dim3(256), 0, stream, cats, ws);
    hipLaunchKernelGGL(k4_prefix,   dim3(1),    dim3(64),  0, stream, ws);
    hipLaunchKernelGGL(k4b_scatter, dim3(64),   dim3(256), 0, stream, cats, ws);
    hipLaunchKernelGGL(k5_mfma,     dim3(528),  dim3(512), 0, stream,
                       Fb, W1T, Wc, bias, shifts, seglens, ws, out);
}